// Round 1
// baseline (130.140 us; speedup 1.0000x reference)
//
#include <hip/hip_runtime.h>

// out[t,c] = bias[c] + sum_{k=0..99} w_norm[k,c] * x[t+k-99, c]   (x zero-padded t<0)
// T=16384, NC=2048, FW=100, all float32.

#define T_TOT 16384
#define NCH   2048
#define FW    100
#define CB    32          // channels per block
#define TB    128         // time steps per chunk
#define RING  256         // ring rows (power of 2)
#define MROWS 24          // mirror rows so static offsets never wrap
#define BROWS (RING + MROWS)
#define NTHR  256
#define TTH   16          // outputs per thread per chunk (TB / 8 groups)
#define UK    10          // k-unroll (100 = 10 * 10)
#define NKC   (FW / UK)
#define NSEG  12          // 64 cgroups * 12 = 768 blocks = 3/CU exactly
#define NCHUNK_TOT (T_TOT / TB)   // 128

__global__ __launch_bounds__(NTHR)
void catent_fir(const float* __restrict__ x,
                const float* __restrict__ wraw,
                const float* __restrict__ bias,
                float* __restrict__ out) {
    __shared__ float ring[BROWS * CB];   // 280*32*4 = 35840 B
    __shared__ float wlds[FW * CB];      // 12800 B
    __shared__ float scl[CB];

    const int tid   = threadIdx.x;
    const int cgrp  = blockIdx.x & 63;
    const int sidx  = blockIdx.x >> 6;          // 0..NSEG-1
    const int cbase = cgrp * CB;

    const int ch0 = (sidx * NCHUNK_TOT) / NSEG;       // first chunk (inclusive)
    const int ch1 = ((sidx + 1) * NCHUNK_TOT) / NSEG; // last chunk (exclusive)
    const int tseg0 = ch0 * TB;

    // ---- weights: load + relu into LDS ----
    for (int i = tid; i < FW * CB; i += NTHR) {
        int k = i >> 5, c = i & 31;
        wlds[i] = fmaxf(wraw[(size_t)k * NCH + cbase + c], 0.0f);
    }
    __syncthreads();
    // per-channel L2 norm scale (one lane per channel; cheap, once per block)
    if (tid < CB) {
        float s = 0.0f;
        #pragma unroll 4
        for (int k = 0; k < FW; ++k) { float v = wlds[k * CB + tid]; s = fmaf(v, v, s); }
        scl[tid] = rsqrtf(fmaxf(s, 1e-12f));
    }
    __syncthreads();
    for (int i = tid; i < FW * CB; i += NTHR) wlds[i] *= scl[i & 31];

    // ---- prologue: stage times [tseg0-128, tseg0+127] into ring row (t & 255) ----
    for (int p = 0; p < 8; ++p) {
        int idx = tid + p * NTHR;        // 0..2047 float4 units (256 rows * 8)
        int row = idx >> 3;              // 0..255
        int c4  = (idx & 7) * 4;
        int t   = tseg0 - TB + row;
        float4 v = make_float4(0.f, 0.f, 0.f, 0.f);
        if (t >= 0) v = *reinterpret_cast<const float4*>(&x[(size_t)t * NCH + cbase + c4]);
        int r = t & (RING - 1);          // two's-complement & handles t<0
        *reinterpret_cast<float4*>(&ring[r * CB + c4]) = v;
        if (r < MROWS)
            *reinterpret_cast<float4*>(&ring[(RING + r) * CB + c4]) = v;
    }
    __syncthreads();   // also covers wlds scaling

    const int c = tid & 31;
    const int g = tid >> 5;              // 0..7 time groups
    const float biasr = bias[cbase + c];

    // per-thread staging piece coords (constant across chunks)
    const int r0  = tid >> 3;            // 0..31
    const int sc4 = (tid & 7) * 4;

    for (int ch = ch0; ch < ch1; ++ch) {
        const int t0 = ch * TB;
        const bool do_stage = (ch + 1 < ch1);

        // T14: issue next-chunk global loads early; ds_write after the drain barrier
        float4 st[4];
        if (do_stage) {
            const size_t gb = (size_t)(t0 + TB) * NCH + cbase + sc4;
            #pragma unroll
            for (int p = 0; p < 4; ++p)
                st[p] = *reinterpret_cast<const float4*>(&x[gb + (size_t)(r0 + p * 32) * NCH]);
        }

        // ---- compute 16 outputs per thread ----
        float acc[TTH];
        #pragma unroll
        for (int i = 0; i < TTH; ++i) acc[i] = biasr;

        const int rowbase0 = t0 - (FW - 1) + g * TTH;   // absolute time of (kc=0, j=0)
        #pragma unroll 1
        for (int kc = 0; kc < NKC; ++kc) {
            const int br = (rowbase0 + kc * UK) & (RING - 1);   // start row; +24 max stays < BROWS
            const float* xb = &ring[br * CB + c];
            const float* wb = &wlds[(kc * UK) * CB + c];
            float wk[UK];
            #pragma unroll
            for (int u = 0; u < UK; ++u) wk[u] = wb[u * CB];
            float xj[TTH + UK - 1];
            #pragma unroll
            for (int j = 0; j < TTH + UK - 1; ++j) xj[j] = xb[j * CB];
            #pragma unroll
            for (int u = 0; u < UK; ++u)
                #pragma unroll
                for (int t = 0; t < TTH; ++t)
                    acc[t] = fmaf(wk[u], xj[t + u], acc[t]);
        }

        // ---- store outputs (coalesced: 32 consecutive channels per half-wave) ----
        {
            size_t ob = (size_t)(t0 + g * TTH) * NCH + cbase + c;
            #pragma unroll
            for (int t = 0; t < TTH; ++t) out[ob + (size_t)t * NCH] = acc[t];
        }

        __syncthreads();   // all ring reads of this chunk done

        if (do_stage) {
            const int rbase = (t0 + TB) & (RING - 1);   // 0 or 128
            #pragma unroll
            for (int p = 0; p < 4; ++p) {
                int r = rbase + r0 + p * 32;
                *reinterpret_cast<float4*>(&ring[r * CB + sc4]) = st[p];
                if (r < MROWS)
                    *reinterpret_cast<float4*>(&ring[(RING + r) * CB + sc4]) = st[p];
            }
        }
        __syncthreads();   // staged rows visible for next chunk
    }
}

extern "C" void kernel_launch(void* const* d_in, const int* in_sizes, int n_in,
                              void* d_out, int out_size, void* d_ws, size_t ws_size,
                              hipStream_t stream) {
    const float* x    = (const float*)d_in[0];   // [T, NC]
    const float* wraw = (const float*)d_in[1];   // [FW, NC]
    const float* bias = (const float*)d_in[2];   // [1, NC]
    float* out = (float*)d_out;                  // [T, NC]

    dim3 grid(64 * NSEG);   // 768 blocks
    dim3 block(NTHR);
    catent_fir<<<grid, block, 0, stream>>>(x, wraw, bias, out);
}

// Round 2
// 111.602 us; speedup vs baseline: 1.1661x; 1.1661x over previous
//
#include <hip/hip_runtime.h>

// out[t,c] = bias[c] + sum_{k=0..99} w_norm[k,c] * x[t+k-99, c]   (x zero-padded t<0)
// T=16384, NC=2048, FW=100, all float32.
// Channel-major LDS ring (ds_read_b128), register sliding window, 104-tap aligned filter.

#define T_TOT 16384
#define NCH   2048
#define FW    100
#define CB    32          // channels per block
#define TB    128         // time steps per chunk
#define NTHR  256
#define TTH   16          // outputs per thread per chunk
#define ROWL  292         // ring row length (floats): 256 ring + 36 mirror; 292/4=73 odd => b128 bank spread
#define WROW  108         // weight row length: 104 taps + pad; 108/4=27 odd
#define NSEG  12          // 64 cgroups * 12 = 768 blocks = 3/CU (LDS-limited residency 3)
#define NCHUNK_TOT (T_TOT / TB)   // 128

// One K-chunk of 8 taps: load 8 new x into slots NS..NS+7, 8 w, do 128 FMAs at phase PH.
#define KC_PHASE(PH, NS) do {                                                   \
    int ro_ = tk & 255;                                                         \
    float4 n0_ = *(const float4*)(rrow + ro_);                                  \
    float4 n1_ = *(const float4*)(rrow + ro_ + 4);                              \
    float4 w0_ = *(const float4*)(wp);                                          \
    float4 w1_ = *(const float4*)(wp + 4);                                      \
    float wk_[8];                                                               \
    wk_[0]=w0_.x; wk_[1]=w0_.y; wk_[2]=w0_.z; wk_[3]=w0_.w;                     \
    wk_[4]=w1_.x; wk_[5]=w1_.y; wk_[6]=w1_.z; wk_[7]=w1_.w;                     \
    xw[(NS)+0]=n0_.x; xw[(NS)+1]=n0_.y; xw[(NS)+2]=n0_.z; xw[(NS)+3]=n0_.w;     \
    xw[(NS)+4]=n1_.x; xw[(NS)+5]=n1_.y; xw[(NS)+6]=n1_.z; xw[(NS)+7]=n1_.w;     \
    _Pragma("unroll")                                                           \
    for (int u_ = 0; u_ < 8; ++u_) {                                            \
      _Pragma("unroll")                                                         \
      for (int i_ = 0; i_ < 16; ++i_)                                           \
        acc[i_] = fmaf(wk_[u_], xw[((PH) + u_ + i_) % 24], acc[i_]);            \
    }                                                                           \
    tk += 8; wp += 8;                                                           \
} while (0)

__global__ __launch_bounds__(NTHR)
void catent_fir(const float* __restrict__ x,
                const float* __restrict__ wraw,
                const float* __restrict__ bias,
                float* __restrict__ out) {
    __shared__ float ring[CB * ROWL];   // 37376 B, channel-major: ring[c*ROWL + (t&255)]
    __shared__ float wl[CB * WROW];     // 13824 B, channel-major, taps shifted +1 (w'[0]=0)
    __shared__ float scl[CB];

    const int tid   = threadIdx.x;
    const int cgrp  = blockIdx.x & 63;
    const int sidx  = blockIdx.x >> 6;
    const int cbase = cgrp * CB;

    const int ch0 = (sidx * NCHUNK_TOT) / NSEG;
    const int ch1 = ((sidx + 1) * NCHUNK_TOT) / NSEG;
    const int tseg0 = ch0 * TB;

    const int c = tid & 31;
    const int g = tid >> 5;              // 0..7 (time group; also staging row group)

    // ---- weights: relu, transpose into LDS (shifted by 1: wl[c][k+1] = relu(w[k][c])) ----
    for (int i = tid; i < FW * CB; i += NTHR) {
        int k = i >> 5, cc = i & 31;
        wl[cc * WROW + k + 1] = fmaxf(wraw[(size_t)k * NCH + cbase + cc], 0.0f);
    }
    if (tid < CB) {
        wl[tid * WROW + 0] = 0.0f;
        for (int j = FW + 1; j < WROW; ++j) wl[tid * WROW + j] = 0.0f;
    }
    __syncthreads();
    if (tid < CB) {
        float s = 0.0f;
        #pragma unroll 4
        for (int k = 1; k <= FW; ++k) { float v = wl[tid * WROW + k]; s = fmaf(v, v, s); }
        scl[tid] = rsqrtf(fmaxf(s, 1e-12f));
    }
    __syncthreads();
    for (int i = tid; i < FW * CB; i += NTHR) {
        int k = i >> 5, cc = i & 31;
        wl[cc * WROW + k + 1] *= scl[cc];
    }

    // ---- prologue: stage times [tseg0-128, tseg0+127]; mirror slots [0,32) -> [256,288) ----
    {
        float* rw = &ring[c * ROWL];
        for (int p = 0; p < 2; ++p) {
            int tbase = tseg0 - TB + p * TB + g * 16;
            float v[16];
            #pragma unroll
            for (int j = 0; j < 16; ++j) {
                int t = tbase + j;
                v[j] = (t >= 0) ? x[(size_t)t * NCH + cbase + c] : 0.0f;
            }
            int rm = tbase & 255;
            #pragma unroll
            for (int q = 0; q < 4; ++q)
                *(float4*)(rw + rm + q * 4) = make_float4(v[q*4], v[q*4+1], v[q*4+2], v[q*4+3]);
            if (rm < 32) {
                #pragma unroll
                for (int q = 0; q < 4; ++q)
                    *(float4*)(rw + 256 + rm + q * 4) = make_float4(v[q*4], v[q*4+1], v[q*4+2], v[q*4+3]);
            }
        }
    }
    __syncthreads();

    const float biasr = bias[cbase + c];
    const float* rrow = &ring[c * ROWL];
    const float* wrow = &wl[c * WROW];
    float* rwr = &ring[c * ROWL];

    for (int ch = ch0; ch < ch1; ++ch) {
        const int t0 = ch * TB;
        const bool do_stage = (ch + 1 < ch1);

        // T14: issue next-chunk global loads early (16 scalar, stride NCH, coalesced per instr)
        float stv[16];
        if (do_stage) {
            const size_t gb = (size_t)(t0 + TB + g * 16) * NCH + cbase + c;
            #pragma unroll
            for (int j = 0; j < 16; ++j) stv[j] = x[gb + (size_t)j * NCH];
        }

        float acc[16];
        #pragma unroll
        for (int i = 0; i < 16; ++i) acc[i] = biasr;

        float xw[24];
        const int base0 = t0 + g * 16 - 100;     // multiple of 4 => 16B-aligned ring reads

        // kc = 0: fill window x[base0 .. base0+23], taps j=0..7 (w'[0]=0)
        {
            int ro = base0 & 255;
            #pragma unroll
            for (int q = 0; q < 6; ++q) {
                float4 v = *(const float4*)(rrow + ro + q * 4);
                xw[q*4+0] = v.x; xw[q*4+1] = v.y; xw[q*4+2] = v.z; xw[q*4+3] = v.w;
            }
            float4 w0 = *(const float4*)(wrow);
            float4 w1 = *(const float4*)(wrow + 4);
            float wk[8];
            wk[0]=w0.x; wk[1]=w0.y; wk[2]=w0.z; wk[3]=w0.w;
            wk[4]=w1.x; wk[5]=w1.y; wk[6]=w1.z; wk[7]=w1.w;
            #pragma unroll
            for (int u = 0; u < 8; ++u) {
                #pragma unroll
                for (int i = 0; i < 16; ++i)
                    acc[i] = fmaf(wk[u], xw[(u + i) % 24], acc[i]);
            }
        }

        // kc = 1..12: slide by 8 (register rotation, phase period 3)
        int tk = base0 + 24;                 // = base_kc + 16 for kc=1
        const float* wp = wrow + 8;
        #pragma unroll 1
        for (int m = 0; m < 4; ++m) {
            KC_PHASE(8, 0);    // kc = 3m+1
            KC_PHASE(16, 8);   // kc = 3m+2
            KC_PHASE(0, 16);   // kc = 3m+3
        }

        __syncthreads();   // all ring reads of this chunk done

        if (do_stage) {
            int rm = (t0 + TB + g * 16) & 255;
            #pragma unroll
            for (int q = 0; q < 4; ++q)
                *(float4*)(rwr + rm + q * 4) = make_float4(stv[q*4], stv[q*4+1], stv[q*4+2], stv[q*4+3]);
            if (rm < 32) {
                #pragma unroll
                for (int q = 0; q < 4; ++q)
                    *(float4*)(rwr + 256 + rm + q * 4) = make_float4(stv[q*4], stv[q*4+1], stv[q*4+2], stv[q*4+3]);
            }
        }
        __syncthreads();   // staged rows visible for next chunk

        // stores last: they drain during the next chunk's compute, not at a barrier
        {
            size_t ob = (size_t)(t0 + g * 16) * NCH + cbase + c;
            #pragma unroll
            for (int i = 0; i < 16; ++i) out[ob + (size_t)i * NCH] = acc[i];
        }
    }
}

extern "C" void kernel_launch(void* const* d_in, const int* in_sizes, int n_in,
                              void* d_out, int out_size, void* d_ws, size_t ws_size,
                              hipStream_t stream) {
    const float* x    = (const float*)d_in[0];   // [T, NC]
    const float* wraw = (const float*)d_in[1];   // [FW, NC]
    const float* bias = (const float*)d_in[2];   // [1, NC]
    float* out = (float*)d_out;                  // [T, NC]

    dim3 grid(64 * NSEG);   // 768 blocks = 3/CU
    dim3 block(NTHR);
    catent_fir<<<grid, block, 0, stream>>>(x, wraw, bias, out);
}

// Round 4
// 107.079 us; speedup vs baseline: 1.2154x; 1.0422x over previous
//
#include <hip/hip_runtime.h>

// out[t,c] = bias[c] + sum_{k=0..99} w_norm[k,c] * x[t+k-99, c]   (x zero-padded t<0)
// T=16384, NC=2048, FW=100, all float32.
// Channel-major LDS ring (ds_read_b128) for x; ALL 104 taps held in registers
// (loaded+normalized per segment); register sliding window for x.
// Mirror region: slots [0,32) duplicated at [256,288) -- covers max read 275;
// rm<32 writes stay < ROWL=292 (rm=32 would overflow into the next row: R3 bug).

#define T_TOT 16384
#define NCH   2048
#define FW    100
#define CB    32          // channels per block
#define TB    128         // time steps per chunk
#define NTHR  256
#define ROWL  292         // ring row length (floats): 256 ring + 36 pad; rows 16B-aligned
#define NSEG  8           // 64 cgroups * 8 = 512 blocks = exactly 2/CU
#define NCHUNK (T_TOT / TB / NSEG)   // 16 chunks per segment

// One K-chunk of 8 taps (taps j = KI*8 .. KI*8+7 of the 104-tap shifted filter):
// load 8 new x floats into window slots NS..NS+7, 128 FMAs at phase PH.
#define KC_STEP(KI, PH, NS) do {                                                \
    int ro_ = (base0 + (KI)*8 + 16) & 255;                                      \
    float4 n0_ = *(const float4*)(rrow + ro_);                                  \
    float4 n1_ = *(const float4*)(rrow + ro_ + 4);                              \
    xw[(NS)+0]=n0_.x; xw[(NS)+1]=n0_.y; xw[(NS)+2]=n0_.z; xw[(NS)+3]=n0_.w;     \
    xw[(NS)+4]=n1_.x; xw[(NS)+5]=n1_.y; xw[(NS)+6]=n1_.z; xw[(NS)+7]=n1_.w;     \
    _Pragma("unroll")                                                           \
    for (int u_ = 0; u_ < 8; ++u_) {                                            \
      _Pragma("unroll")                                                         \
      for (int i_ = 0; i_ < 16; ++i_)                                           \
        acc[i_] = fmaf(wreg[(KI)*8 + u_], xw[((PH) + u_ + i_) % 24], acc[i_]);  \
    }                                                                           \
} while (0)

__global__ __launch_bounds__(NTHR, 2)
void catent_fir(const float* __restrict__ x,
                const float* __restrict__ wraw,
                const float* __restrict__ bias,
                float* __restrict__ out) {
    __shared__ __align__(16) float ring[CB * ROWL];   // 37376 B, ring[c*ROWL + (t&255)]

    const int tid   = threadIdx.x;
    const int cgrp  = blockIdx.x & 63;
    const int sidx  = blockIdx.x >> 6;          // 0..NSEG-1
    const int cbase = cgrp * CB;

    const int ch0 = sidx * NCHUNK;
    const int tseg0 = ch0 * TB;

    const int c = tid & 31;
    const int g = tid >> 5;              // 0..7 time groups

    // ---- weights into registers: w'[0]=0, w'[j]=relu(w[j-1][c])*scl, w'[101..103]=0 ----
    float wreg[104];
    {
        const float* wcol = wraw + cbase + c;
        float s = 0.0f;
        wreg[0] = 0.0f;
        #pragma unroll
        for (int j = 1; j <= FW; ++j) {
            float v = fmaxf(wcol[(size_t)(j - 1) * NCH], 0.0f);
            wreg[j] = v;
            s = fmaf(v, v, s);
        }
        wreg[101] = 0.0f; wreg[102] = 0.0f; wreg[103] = 0.0f;
        float scl = rsqrtf(fmaxf(s, 1e-12f));
        #pragma unroll
        for (int j = 1; j <= FW; ++j) wreg[j] *= scl;
    }

    // ---- prologue: stage times [tseg0-128, tseg0+127]; mirror slots [0,32) -> [256,288) ----
    {
        float* rw = &ring[c * ROWL];
        for (int p = 0; p < 2; ++p) {
            int tbase = tseg0 - TB + p * TB + g * 16;
            float v[16];
            #pragma unroll
            for (int j = 0; j < 16; ++j) {
                int t = tbase + j;
                v[j] = (t >= 0) ? x[(size_t)t * NCH + cbase + c] : 0.0f;
            }
            int rm = tbase & 255;
            #pragma unroll
            for (int q = 0; q < 4; ++q)
                *(float4*)(rw + rm + q * 4) = make_float4(v[q*4], v[q*4+1], v[q*4+2], v[q*4+3]);
            if (rm < 32) {
                #pragma unroll
                for (int q = 0; q < 4; ++q)
                    *(float4*)(rw + 256 + rm + q * 4) = make_float4(v[q*4], v[q*4+1], v[q*4+2], v[q*4+3]);
            }
        }
    }
    __syncthreads();

    const float biasr = bias[cbase + c];
    const float* rrow = &ring[c * ROWL];
    float* rwr = &ring[c * ROWL];

    for (int ch = ch0; ch < ch0 + NCHUNK; ++ch) {
        const int t0 = ch * TB;
        const bool do_stage = (ch + 1 < ch0 + NCHUNK);

        // T14: issue next-chunk global loads early; ds_write after the drain barrier
        float stv[16];
        if (do_stage) {
            const size_t gb = (size_t)(t0 + TB + g * 16) * NCH + cbase + c;
            #pragma unroll
            for (int j = 0; j < 16; ++j) stv[j] = x[gb + (size_t)j * NCH];
        }

        float acc[16];
        #pragma unroll
        for (int i = 0; i < 16; ++i) acc[i] = biasr;

        float xw[24];
        const int base0 = t0 + g * 16 - 100;     // multiple of 4 => 16B-aligned ring reads

        // kc = 0: fill window x[base0 .. base0+23], taps j=0..7 (w'[0]=0)
        {
            int ro = base0 & 255;
            #pragma unroll
            for (int q = 0; q < 6; ++q) {
                float4 v = *(const float4*)(rrow + ro + q * 4);
                xw[q*4+0] = v.x; xw[q*4+1] = v.y; xw[q*4+2] = v.z; xw[q*4+3] = v.w;
            }
            #pragma unroll
            for (int u = 0; u < 8; ++u) {
                #pragma unroll
                for (int i = 0; i < 16; ++i)
                    acc[i] = fmaf(wreg[u], xw[(u + i) % 24], acc[i]);
            }
        }

        // kc = 1..12: slide by 8 (register rotation, phase period 3).
        // Taps 101..103 are zero; their (stale but finite) x reads contribute 0.
        KC_STEP(1,  8, 0);
        KC_STEP(2, 16, 8);
        KC_STEP(3,  0, 16);
        KC_STEP(4,  8, 0);
        KC_STEP(5, 16, 8);
        KC_STEP(6,  0, 16);
        KC_STEP(7,  8, 0);
        KC_STEP(8, 16, 8);
        KC_STEP(9,  0, 16);
        KC_STEP(10, 8, 0);
        KC_STEP(11,16, 8);
        KC_STEP(12, 0, 16);

        __syncthreads();   // all ring reads of this chunk done

        if (do_stage) {
            int rm = (t0 + TB + g * 16) & 255;
            #pragma unroll
            for (int q = 0; q < 4; ++q)
                *(float4*)(rwr + rm + q * 4) = make_float4(stv[q*4], stv[q*4+1], stv[q*4+2], stv[q*4+3]);
            if (rm < 32) {
                #pragma unroll
                for (int q = 0; q < 4; ++q)
                    *(float4*)(rwr + 256 + rm + q * 4) = make_float4(stv[q*4], stv[q*4+1], stv[q*4+2], stv[q*4+3]);
            }
        }
        __syncthreads();   // staged rows visible for next chunk

        // stores last: they drain during the next chunk's compute, not at a barrier
        {
            size_t ob = (size_t)(t0 + g * 16) * NCH + cbase + c;
            #pragma unroll
            for (int i = 0; i < 16; ++i) out[ob + (size_t)i * NCH] = acc[i];
        }
    }
}

extern "C" void kernel_launch(void* const* d_in, const int* in_sizes, int n_in,
                              void* d_out, int out_size, void* d_ws, size_t ws_size,
                              hipStream_t stream) {
    const float* x    = (const float*)d_in[0];   // [T, NC]
    const float* wraw = (const float*)d_in[1];   // [FW, NC]
    const float* bias = (const float*)d_in[2];   // [1, NC]
    float* out = (float*)d_out;                  // [T, NC]

    dim3 grid(64 * NSEG);   // 512 blocks = exactly 2/CU
    dim3 block(NTHR);
    catent_fir<<<grid, block, 0, stream>>>(x, wraw, bias, out);
}